// Round 12
// baseline (275.127 us; speedup 1.0000x reference)
//
#include <hip/hip_runtime.h>
#include <hip/hip_bf16.h>
#include <math.h>

#define B_SZ 8
#define L_SZ 4096
#define D_SZ 1024
#define CHT  64
#define NCH  (L_SZ / CHT)

typedef __bf16 bf16_t;
typedef bf16_t bf16x8 __attribute__((ext_vector_type(8)));
typedef bf16_t bf16x4 __attribute__((ext_vector_type(4)));
typedef float  f32x4  __attribute__((ext_vector_type(4)));

#define BM 256
#define BN 256
#define BK 32
#define NT 32              // K-tiles (1024/32)
#define BUFB 32768         // per ring slot: A 16KB + B 16KB
#define EP_P 68            // epilogue strip padded width (f32)

__device__ __forceinline__ void gld16(const void* g, void* l) {
  __builtin_amdgcn_global_load_lds(
      (const __attribute__((address_space(1))) void*)g,
      (__attribute__((address_space(3))) void*)l, 16, 0, 0);
}

#define MFMA16(a, b, c) __builtin_amdgcn_mfma_f32_16x16x32_bf16(a, b, c, 0, 0, 0)

// ============================================================================
// GEMM1: C[m,n] = sum_k u[m,k]*Wb[n,k]; u FP32 (reg-staged + cvt -> LDS),
// Wb bf16 via global_load_lds. 256x256, 8 waves (2Mx4N), BK=32, 3-slot ring,
// counted vmcnt(6), ONE barrier per K-tile. Row-pair 3-bit swizzle on both
// A (direct LDS-side, reg-staged) and B (inverse-global, rule 21).
// Fused per-64-chunk scan in epilogue, chunk finals -> cf.
// ============================================================================
__global__ __launch_bounds__(512, 1)
void gemm1_k(const float* __restrict__ U, const bf16_t* __restrict__ Wt,
             bf16_t* __restrict__ Cg, const float* __restrict__ pw,
             float* __restrict__ cf) {
  __shared__ __align__(16) char smem[3 * BUFB];   // 96 KiB; epilogue strip aliases
  const int tid  = threadIdx.x;
  const int lane = tid & 63;
  const int wave = tid >> 6;
  const int wm = wave >> 2, wn = wave & 3;
  const int fr = lane & 15, g = lane >> 4;

  const int flat = (blockIdx.x & 7) * 64 + (blockIdx.x >> 3);
  const int bx = flat & 3, by = flat >> 2;
  const int brow = by * BM, bcol = bx * BN;

  // ---- A reg-staging source (fp32): lane -> row r0 = lane>>2 (and +16), chunk c = lane&3
  const float* uA = U + (size_t)(brow + wave * 32 + (lane >> 2)) * 1024 + (lane & 3) * 8;
  // A LDS write addr (swizzled directly): line = r0>>1, slot = ((r0&1)*4|c)^line
  const int r0 = lane >> 2;
  const int awoff = wave * 2048 + (r0 >> 1) * 128 +
                    (((((r0 & 1) << 2) | (lane & 3)) ^ (r0 >> 1)) << 4);

  // ---- B staging source (inverse row-pair swizzle on global addr; LDS dest linear)
  const int ll  = lane >> 3;
  const int sl  = (lane & 7) ^ ll;
  const int srw = ll * 2 + (sl >> 2);
  const int sch = sl & 3;
  const bf16_t* bSrc = Wt + (size_t)(bcol + wave * 32 + srw) * 1024 + sch * 8;
  const int bldsoff = 16384 + wave * 2048;     // B region + per-wave block (THE r11 bug)

  // ---- read side (both A and B): line h = fr>>1, slot = ((fr&1)*4|g)^h
  const int h = fr >> 1;
  const int slotv = (((fr & 1) << 2) | g) ^ h;
  const int aoff = wm * 8192 + h * 128 + slotv * 16;
  const int boff = 16384 + wn * 4096 + h * 128 + slotv * 16;

  f32x4 acc[8][4] = {};
  f32x4 ra0, ra1, ra2, ra3, rb0, rb1, rb2, rb3;

  // prologue: A(0)->ra, A(1)->rb, B(0)/B(1) gld; drain; write A(0); barrier
  {
    const float* g0 = uA;
    ra0 = *(const f32x4*)(g0);              ra1 = *(const f32x4*)(g0 + 4);
    ra2 = *(const f32x4*)(g0 + 16 * 1024);  ra3 = *(const f32x4*)(g0 + 16 * 1024 + 4);
    gld16(bSrc, smem + bldsoff);
    gld16(bSrc + (size_t)16 * 1024, smem + bldsoff + 1024);
    const float* g1 = uA + BK;
    rb0 = *(const f32x4*)(g1);              rb1 = *(const f32x4*)(g1 + 4);
    rb2 = *(const f32x4*)(g1 + 16 * 1024);  rb3 = *(const f32x4*)(g1 + 16 * 1024 + 4);
    gld16(bSrc + BK, smem + BUFB + bldsoff);
    gld16(bSrc + (size_t)16 * 1024 + BK, smem + BUFB + bldsoff + 1024);
  }
  asm volatile("s_waitcnt vmcnt(0)" ::: "memory");
  {
    bf16x8 h0, h1;
#pragma unroll
    for (int j = 0; j < 4; ++j) {
      h0[j] = (bf16_t)ra0[j]; h0[4 + j] = (bf16_t)ra1[j];
      h1[j] = (bf16_t)ra2[j]; h1[4 + j] = (bf16_t)ra3[j];
    }
    *(bf16x8*)(smem + awoff) = h0;
    *(bf16x8*)(smem + awoff + 1024) = h1;
  }
  asm volatile("s_waitcnt lgkmcnt(0)" ::: "memory");
  __builtin_amdgcn_s_barrier();
  asm volatile("" ::: "memory");

  // body: reads tile T from slot T%3; issues B-gld + A-reg loads for T+2 (into F*);
  // MFMA; vmcnt(6) certifies T+1's 6 issues; writes A(T+1) from N*; barrier.
#define BODY(T, N0, N1, N2, N3, F0, F1, F2, F3) do { \
    const char* sb_ = smem + ((T) % 3) * BUFB; \
    bf16x8 af_[8], bv_[4]; \
    _Pragma("unroll") \
    for (int m = 0; m < 8; ++m) af_[m] = *(const bf16x8*)(sb_ + aoff + m * 1024); \
    _Pragma("unroll") \
    for (int n = 0; n < 4; ++n) bv_[n] = *(const bf16x8*)(sb_ + boff + n * 1024); \
    if ((T) + 2 < NT) { \
      char* db_ = smem + (((T) + 2) % 3) * BUFB + bldsoff; \
      const size_t ko_ = (size_t)((T) + 2) * BK; \
      gld16(bSrc + ko_, db_); \
      gld16(bSrc + (size_t)16 * 1024 + ko_, db_ + 1024); \
      const float* gp_ = uA + ko_; \
      F0 = *(const f32x4*)(gp_);              F1 = *(const f32x4*)(gp_ + 4); \
      F2 = *(const f32x4*)(gp_ + 16 * 1024); F3 = *(const f32x4*)(gp_ + 16 * 1024 + 4); \
    } \
    __builtin_amdgcn_s_setprio(1); \
    _Pragma("unroll") \
    for (int m = 0; m < 8; ++m) \
      _Pragma("unroll") \
      for (int n = 0; n < 4; ++n) \
        acc[m][n] = MFMA16(af_[m], bv_[n], acc[m][n]); \
    __builtin_amdgcn_s_setprio(0); \
    if ((T) + 2 < NT) { asm volatile("s_waitcnt vmcnt(6)" ::: "memory"); } \
    else              { asm volatile("s_waitcnt vmcnt(0)" ::: "memory"); } \
    if ((T) + 1 < NT) { \
      char* wb_ = smem + (((T) + 1) % 3) * BUFB; \
      bf16x8 h0_, h1_; \
      _Pragma("unroll") \
      for (int j = 0; j < 4; ++j) { \
        h0_[j] = (bf16_t)N0[j]; h0_[4 + j] = (bf16_t)N1[j]; \
        h1_[j] = (bf16_t)N2[j]; h1_[4 + j] = (bf16_t)N3[j]; \
      } \
      *(bf16x8*)(wb_ + awoff) = h0_; \
      *(bf16x8*)(wb_ + awoff + 1024) = h1_; \
    } \
    asm volatile("s_waitcnt lgkmcnt(0)" ::: "memory"); \
    __builtin_amdgcn_s_barrier(); \
    asm volatile("" ::: "memory"); \
  } while (0)

  for (int t = 0; t < NT; t += 2) {
    BODY(t,     rb0, rb1, rb2, rb3, ra0, ra1, ra2, ra3);
    BODY(t + 1, ra0, ra1, ra2, ra3, rb0, rb1, rb2, rb3);
  }
#undef BODY

  // ---- epilogue: 4 column-strips of 64; fused per-64-chunk scan
  __syncthreads();
  float* strip = (float*)smem;
  const int bb  = by >> 4;
  const int cg0 = (by & 15) * 4;
#pragma unroll 1
  for (int q = 0; q < 4; ++q) {
    if (wn == q) {
#pragma unroll
      for (int mi = 0; mi < 8; ++mi)
#pragma unroll
        for (int ni = 0; ni < 4; ++ni)
#pragma unroll
          for (int r = 0; r < 4; ++r)
            strip[(wm * 128 + mi * 16 + g * 4 + r) * EP_P + ni * 16 + fr] = acc[mi][ni][r];
    }
    __syncthreads();
    if (tid < 256) {
      const int col = tid & 63;
      const int ch  = tid >> 6;
      const int d   = bcol + q * 64 + col;
      const float a = pw[d];
      float s = 0.f;
#pragma unroll 1
      for (int grp = 0; grp < 4; ++grp) {
        float v[16];
#pragma unroll
        for (int u = 0; u < 16; ++u) v[u] = strip[(ch * 64 + grp * 16 + u) * EP_P + col];
#pragma unroll
        for (int u = 0; u < 16; ++u) { s = a * s + v[u]; v[u] = s; }
#pragma unroll
        for (int u = 0; u < 16; ++u) strip[(ch * 64 + grp * 16 + u) * EP_P + col] = v[u];
      }
      cf[((size_t)(bb * NCH + cg0 + ch)) * D_SZ + d] = s;
    }
    __syncthreads();
#pragma unroll
    for (int j = 0; j < 4; ++j) {
      const int u = j * 512 + tid;
      const int row = u >> 3;
      const int cu = (u & 7) * 8;
      f32x4 lo = *(const f32x4*)&strip[row * EP_P + cu];
      f32x4 hi = *(const f32x4*)&strip[row * EP_P + cu + 4];
      bf16x8 h2;
#pragma unroll
      for (int jj = 0; jj < 4; ++jj) { h2[jj] = (bf16_t)lo[jj]; h2[4 + jj] = (bf16_t)hi[jj]; }
      *(bf16x8*)&Cg[(size_t)(brow + row) * 1024 + bcol + q * 64 + cu] = h2;
    }
    __syncthreads();
  }
}

// ============================================================================
// GEMM2: round-10 proven core (A bf16 via gld, 3-slot ring, vmcnt(4),
// one barrier/tile, row-pair swizzle), plain bf16 store epilogue.
// ============================================================================
__global__ __launch_bounds__(512, 1)
void gemm2_k(const bf16_t* __restrict__ A, const bf16_t* __restrict__ Wt,
             bf16_t* __restrict__ Cg) {
  __shared__ __align__(16) char smem[3 * BUFB];
  const int tid  = threadIdx.x;
  const int lane = tid & 63;
  const int wave = tid >> 6;
  const int wm = wave >> 2, wn = wave & 3;
  const int fr = lane & 15, g = lane >> 4;

  const int flat = (blockIdx.x & 7) * 64 + (blockIdx.x >> 3);
  const int bx = flat & 3, by = flat >> 2;
  const int brow = by * BM, bcol = bx * BN;

  const int ll  = lane >> 3;
  const int sl  = (lane & 7) ^ ll;
  const int srw = ll * 2 + (sl >> 2);
  const int sch = sl & 3;
  const bf16_t* aSrc = A  + (size_t)(brow + wave * 32 + srw) * 1024 + sch * 8;
  const bf16_t* bSrc = Wt + (size_t)(bcol + wave * 32 + srw) * 1024 + sch * 8;

  const int h = fr >> 1;
  const int slotv = (((fr & 1) << 2) | g) ^ h;
  const int aoff = wm * 8192 + h * 128 + slotv * 16;
  const int boff = 16384 + wn * 4096 + h * 128 + slotv * 16;

#define STG(DB, T) { \
    char* d_ = (DB) + wave * 2048; \
    const size_t ko_ = (size_t)(T) * BK; \
    gld16(aSrc + ko_, d_); \
    gld16(aSrc + (size_t)16 * 1024 + ko_, d_ + 1024); \
    gld16(bSrc + ko_, d_ + 16384); \
    gld16(bSrc + (size_t)16 * 1024 + ko_, d_ + 17408); \
  }

  f32x4 acc[8][4] = {};
  bf16x8 af[8], bfv[4];

  STG(smem, 0);
  STG(smem + BUFB, 1);
  asm volatile("s_waitcnt vmcnt(4)" ::: "memory");
  __builtin_amdgcn_s_barrier();
  asm volatile("" ::: "memory");

  int bu = 0, bs = 2;
  for (int t = 0; t < NT; ++t) {
    const char* sb = smem + bu * BUFB;
#pragma unroll
    for (int m = 0; m < 8; ++m)
      af[m] = *(const bf16x8*)(sb + aoff + m * 1024);
#pragma unroll
    for (int n = 0; n < 4; ++n)
      bfv[n] = *(const bf16x8*)(sb + boff + n * 1024);
    if (t + 2 < NT) STG(smem + bs * BUFB, t + 2);
    __builtin_amdgcn_s_setprio(1);
#pragma unroll
    for (int m = 0; m < 8; ++m)
#pragma unroll
      for (int n = 0; n < 4; ++n)
        acc[m][n] = MFMA16(af[m], bfv[n], acc[m][n]);
    __builtin_amdgcn_s_setprio(0);
    if (t + 2 < NT) asm volatile("s_waitcnt vmcnt(4)" ::: "memory");
    else            asm volatile("s_waitcnt vmcnt(0)" ::: "memory");
    __builtin_amdgcn_s_barrier();
    asm volatile("" ::: "memory");
    bu = (bu == 2) ? 0 : bu + 1;
    bs = (bs == 2) ? 0 : bs + 1;
  }
#undef STG

  __syncthreads();
  float* strip = (float*)smem;
#pragma unroll 1
  for (int q = 0; q < 4; ++q) {
    if (wn == q) {
#pragma unroll
      for (int mi = 0; mi < 8; ++mi)
#pragma unroll
        for (int ni = 0; ni < 4; ++ni)
#pragma unroll
          for (int r = 0; r < 4; ++r)
            strip[(wm * 128 + mi * 16 + g * 4 + r) * EP_P + ni * 16 + fr] = acc[mi][ni][r];
    }
    __syncthreads();
#pragma unroll
    for (int j = 0; j < 4; ++j) {
      const int u = j * 512 + tid;
      const int row = u >> 3;
      const int cu = (u & 7) * 8;
      f32x4 lo = *(const f32x4*)&strip[row * EP_P + cu];
      f32x4 hi = *(const f32x4*)&strip[row * EP_P + cu + 4];
      bf16x8 h2;
#pragma unroll
      for (int jj = 0; jj < 4; ++jj) { h2[jj] = (bf16_t)lo[jj]; h2[4 + jj] = (bf16_t)hi[jj]; }
      *(bf16x8*)&Cg[(size_t)(brow + row) * 1024 + bcol + q * 64 + cu] = h2;
    }
    __syncthreads();
  }
}

// fp32 -> bf16 grid-stride convert (weights only)
__global__ __launch_bounds__(256)
void conv_bf16_k(const float* __restrict__ src, bf16_t* __restrict__ dst, int n) {
  int i = (blockIdx.x * 256 + threadIdx.x) * 4;
  const int stride = gridDim.x * 256 * 4;
  for (; i < n; i += stride) {
    f32x4 v = *(const f32x4*)(src + i);
    bf16x4 h;
#pragma unroll
    for (int j = 0; j < 4; ++j) h[j] = (bf16_t)v[j];
    *(bf16x4*)(dst + i) = h;
  }
}

// pw[t][d] = a_d^(t+1)
__global__ __launch_bounds__(256)
void pow_k(const float* __restrict__ log_a, float* __restrict__ pw) {
  const int t = blockIdx.x;
  const int d = threadIdx.x * 4;
#pragma unroll
  for (int j = 0; j < 4; ++j)
    pw[t * D_SZ + d + j] = expf(log_a[d + j] * (float)(t + 1));
}

// sequential scan over chunk finals with factor a^CHT, in place
__global__ __launch_bounds__(256)
void scan_carry_k(const float* __restrict__ log_a, float* __restrict__ cf) {
  const int d = blockIdx.x * 256 + threadIdx.x;
  const int b = blockIdx.y;
  const float aT = expf(log_a[d] * (float)CHT);
  float s = 0.f;
  for (int c = 0; c < NCH; ++c) {
    const size_t idx = ((size_t)(b * NCH + c)) * D_SZ + d;
    s = aT * s + cf[idx];
    cf[idx] = s;
  }
}

// states = xb16 + a^(t+1)*S_{c-1}; write bf16 for GEMM2
__global__ __launch_bounds__(128)
void scan_apply_k(const bf16_t* __restrict__ xb16, const float* __restrict__ pw,
                  const float* __restrict__ cf, bf16_t* __restrict__ xs16) {
  const int d8 = threadIdx.x * 8;
  const int l = blockIdx.x;
  const int b = blockIdx.y;
  const int c = l >> 6;
  const int t = l & (CHT - 1);
  const size_t idx = ((size_t)(b * L_SZ + l)) * D_SZ + d8;
  bf16x8 hv = *(const bf16x8*)(xb16 + idx);
  float s[8];
#pragma unroll
  for (int j = 0; j < 8; ++j) s[j] = (float)hv[j];
  if (c > 0) {
    f32x4 p0  = *(const f32x4*)(pw + t * D_SZ + d8);
    f32x4 p1  = *(const f32x4*)(pw + t * D_SZ + d8 + 4);
    const float* cb = cf + ((size_t)(b * NCH + (c - 1))) * D_SZ + d8;
    f32x4 v0 = *(const f32x4*)cb;
    f32x4 v1 = *(const f32x4*)(cb + 4);
#pragma unroll
    for (int j = 0; j < 4; ++j) { s[j] += p0[j] * v0[j]; s[4 + j] += p1[j] * v1[j]; }
  }
  bf16x8 h;
#pragma unroll
  for (int j = 0; j < 8; ++j) h[j] = (bf16_t)s[j];
  *(bf16x8*)(xs16 + idx) = h;
}

// LayerNorm over D=1024 (bf16 input, fp32 output), one block per row
__global__ __launch_bounds__(256)
void ln_k(const bf16_t* __restrict__ y, const float* __restrict__ gamma,
          const float* __restrict__ beta, float* __restrict__ out) {
  const size_t row = blockIdx.x;
  const int tid = threadIdx.x;
  bf16x4 h = *(const bf16x4*)(y + row * D_SZ + tid * 4);
  float v[4];
#pragma unroll
  for (int j = 0; j < 4; ++j) v[j] = (float)h[j];
  float s  = v[0] + v[1] + v[2] + v[3];
  float sq = v[0] * v[0] + v[1] * v[1] + v[2] * v[2] + v[3] * v[3];
#pragma unroll
  for (int off = 32; off; off >>= 1) {
    s  += __shfl_down(s, off);
    sq += __shfl_down(sq, off);
  }
  __shared__ float red[8];
  const int wid = tid >> 6;
  if ((tid & 63) == 0) { red[wid] = s; red[4 + wid] = sq; }
  __syncthreads();
  s  = red[0] + red[1] + red[2] + red[3];
  sq = red[4] + red[5] + red[6] + red[7];
  const float mean = s * (1.f / D_SZ);
  const float var  = sq * (1.f / D_SZ) - mean * mean;
  const float inv  = rsqrtf(var + 1e-5f);
  f32x4 gm = *(const f32x4*)(gamma + tid * 4);
  f32x4 bt = *(const f32x4*)(beta  + tid * 4);
  f32x4 o;
#pragma unroll
  for (int j = 0; j < 4; ++j) o[j] = (v[j] - mean) * inv * gm[j] + bt[j];
  *(f32x4*)(out + row * D_SZ + tid * 4) = o;
}

extern "C" void kernel_launch(void* const* d_in, const int* in_sizes, int n_in,
                              void* d_out, int out_size, void* d_ws, size_t ws_size,
                              hipStream_t stream) {
  const float* u     = (const float*)d_in[0];
  const float* log_a = (const float*)d_in[1];
  const float* W_b   = (const float*)d_in[2];
  const float* W_c   = (const float*)d_in[3];
  const float* gamma = (const float*)d_in[4];
  const float* beta  = (const float*)d_in[5];
  float* out = (float*)d_out;

  const size_t NBLD = (size_t)B_SZ * L_SZ * D_SZ;
  bf16_t* xs16 = (bf16_t*)d_ws;             // bf16 states (apply output)
  bf16_t* xb16 = xs16 + NBLD;               // GEMM1 out (locally scanned); y16 aliases
  bf16_t* wb16 = xb16 + NBLD;
  bf16_t* wc16 = wb16 + (size_t)D_SZ * D_SZ;
  float*  cf   = (float*)(wc16 + (size_t)D_SZ * D_SZ);
  float*  pw   = cf + (size_t)B_SZ * NCH * D_SZ;
  bf16_t* y16  = xb16;                      // xb16 dead after apply

  const int nblk = (B_SZ * L_SZ / BM) * (D_SZ / BN);   // 512

  conv_bf16_k<<<512, 256, 0, stream>>>(W_b, wb16, D_SZ * D_SZ);
  conv_bf16_k<<<512, 256, 0, stream>>>(W_c, wc16, D_SZ * D_SZ);
  pow_k<<<CHT, 256, 0, stream>>>(log_a, pw);

  gemm1_k<<<nblk, 512, 0, stream>>>(u, wb16, xb16, pw, cf);
  scan_carry_k<<<dim3(D_SZ / 256, B_SZ), 256, 0, stream>>>(log_a, cf);
  scan_apply_k<<<dim3(L_SZ, B_SZ), 128, 0, stream>>>(xb16, pw, cf, xs16);
  gemm2_k<<<nblk, 512, 0, stream>>>(xs16, wc16, y16);
  ln_k<<<B_SZ * L_SZ, 256, 0, stream>>>(y16, gamma, beta, out);
}

// Round 13
// 253.770 us; speedup vs baseline: 1.0842x; 1.0842x over previous
//
#include <hip/hip_runtime.h>
#include <hip/hip_bf16.h>
#include <math.h>

#define B_SZ 8
#define L_SZ 4096
#define D_SZ 1024
#define CHT  64
#define NCH  (L_SZ / CHT)

typedef __bf16 bf16_t;
typedef bf16_t bf16x8 __attribute__((ext_vector_type(8)));
typedef bf16_t bf16x4 __attribute__((ext_vector_type(4)));
typedef float  f32x4  __attribute__((ext_vector_type(4)));

#define BM 256
#define BN 256
#define BK 64
#define NT 16              // K-tiles (1024/64)
#define EP_P 68            // epilogue strip padded width (f32)

__device__ __forceinline__ void gld16(const void* g, void* l) {
  __builtin_amdgcn_global_load_lds(
      (const __attribute__((address_space(1))) void*)g,
      (__attribute__((address_space(3))) void*)l, 16, 0, 0);
}

#define MFMA16(a, b, c) __builtin_amdgcn_mfma_f32_16x16x32_bf16(a, b, c, 0, 0, 0)

// C[m,n] = sum_k A[m,k]*Wt[n,k]; A,Wt bf16 row-major [.,1024]; C bf16.
// 256x256 tile, 8 waves (2M x 4N, wave tile 128x64), BK=64.
// 2-dbuf LDS (A: 2x32KB @0, B: 2x32KB @64KB), half-tile staggered staging,
// 4 phases/K-tile a 16 MFMA (quadrants mi-half x ni-half, frag reuse),
// 3-bit XOR chunk swizzle: LDS[row][ch] = global[row][ch ^ (row&7)] (16B chunks).
// MODE 0: fused per-64-chunk scan in epilogue, chunk finals -> cf.
// MODE 1: plain bf16 store.
template<int MODE>
__global__ __launch_bounds__(512, 2)
void gemm256(const bf16_t* __restrict__ A, const bf16_t* __restrict__ Wt,
             bf16_t* __restrict__ Cg, const float* __restrict__ pw,
             float* __restrict__ cf) {
  __shared__ __align__(16) char smem[131072];   // 128 KiB; epilogue strip aliases
  const int tid  = threadIdx.x;
  const int lane = tid & 63;
  const int wave = tid >> 6;
  const int wm = wave >> 2, wn = wave & 3;      // 2M x 4N
  const int fr = lane & 15, g = lane >> 4;

  // XCD-chunked bijective swizzle: 512 blocks = 8 XCDs x 64
  const int flat = (blockIdx.x & 7) * 64 + (blockIdx.x >> 3);
  const int bx = flat & 3, by = flat >> 2;
  const int brow = by * BM, bcol = bx * BN;

  // ---- staging source (pre-swizzled global; LDS dest linear)
  const int srow = lane >> 3;                   // 0..7
  const int sc   = (lane & 7) ^ srow;           // swizzled 16B chunk
  const bf16_t* aSrc = A  + (size_t)(brow + wave * 8 + srow) * 1024 + sc * 8;
  const bf16_t* bSrc = Wt + (size_t)(bcol + wave * 8 + srow) * 1024 + sc * 8;

  // ---- read side: global chunk c of row r is at LDS chunk c^(r&7); r&7 == fr&7
  const int c0 = ((g)     ^ (fr & 7)) << 4;     // kstep 0
  const int c1 = ((4 + g) ^ (fr & 7)) << 4;     // kstep 1
  const int aoff = wm * 16384 + fr * 128;               // + slot*32768 + mi*2048
  const int boff = 65536 + (wn >> 1) * 16384 + ((wn & 1) * 64 + fr) * 128;  // + slot*32768 + ni*2048

  // stage half-tile (H) sub-group (I) of K-tile T into buffer base DB
#define STG_A(DB, H, I, T) gld16(aSrc + (size_t)((H) * 128 + (I) * 64) * 1024 + (T) * 64, \
                                 (DB) + (H) * 16384 + (I) * 8192 + wave * 1024)
#define STG_B(DB, H, I, T) gld16(bSrc + (size_t)((H) * 128 + (I) * 64) * 1024 + (T) * 64, \
                                 (DB) + 65536 + (H) * 16384 + (I) * 8192 + wave * 1024)

  f32x4 acc[8][4] = {};
  bf16x8 af[4][2], bfv[4][2];

  // prologue: stage K-tile 0 into slot 0
  {
    char* db = smem;
    STG_A(db, 0, 0, 0); STG_A(db, 0, 1, 0); STG_A(db, 1, 0, 0); STG_A(db, 1, 1, 0);
    STG_B(db, 0, 0, 0); STG_B(db, 0, 1, 0); STG_B(db, 1, 0, 0); STG_B(db, 1, 1, 0);
  }
  asm volatile("s_waitcnt vmcnt(0)" ::: "memory");
  __builtin_amdgcn_s_barrier();
  asm volatile("" ::: "memory");

  for (int t = 0; t < NT; ++t) {
    const int s = t & 1;
    const char* sb = smem + s * 32768;
    char* db = smem + (s ^ 1) * 32768;
    const bool pf = (t + 1 < NT);

    // ===== phase 1: read A mi0-3 (8) + B ni0-1 (4); stage next A-half0
#pragma unroll
    for (int m = 0; m < 4; ++m) {
      af[m][0] = *(const bf16x8*)(sb + aoff + m * 2048 + c0);
      af[m][1] = *(const bf16x8*)(sb + aoff + m * 2048 + c1);
    }
#pragma unroll
    for (int n = 0; n < 2; ++n) {
      bfv[n][0] = *(const bf16x8*)(sb + boff + n * 2048 + c0);
      bfv[n][1] = *(const bf16x8*)(sb + boff + n * 2048 + c1);
    }
    if (pf) { STG_A(db, 0, 0, t + 1); STG_A(db, 0, 1, t + 1); }
    __builtin_amdgcn_s_barrier(); asm volatile("" ::: "memory");
    __builtin_amdgcn_s_setprio(1);
#pragma unroll
    for (int m = 0; m < 4; ++m)
#pragma unroll
      for (int n = 0; n < 2; ++n) {
        acc[m][n] = MFMA16(af[m][0], bfv[n][0], acc[m][n]);
        acc[m][n] = MFMA16(af[m][1], bfv[n][1], acc[m][n]);
      }
    __builtin_amdgcn_s_setprio(0);
    __builtin_amdgcn_s_barrier(); asm volatile("" ::: "memory");

    // ===== phase 2: read B ni2-3 (4); stage next A-half1 + B-half0(i0)
#pragma unroll
    for (int n = 2; n < 4; ++n) {
      bfv[n][0] = *(const bf16x8*)(sb + boff + n * 2048 + c0);
      bfv[n][1] = *(const bf16x8*)(sb + boff + n * 2048 + c1);
    }
    if (pf) { STG_A(db, 1, 0, t + 1); STG_A(db, 1, 1, t + 1); STG_B(db, 0, 0, t + 1); }
    __builtin_amdgcn_s_barrier(); asm volatile("" ::: "memory");
    __builtin_amdgcn_s_setprio(1);
#pragma unroll
    for (int m = 0; m < 4; ++m)
#pragma unroll
      for (int n = 2; n < 4; ++n) {
        acc[m][n] = MFMA16(af[m][0], bfv[n][0], acc[m][n]);
        acc[m][n] = MFMA16(af[m][1], bfv[n][1], acc[m][n]);
      }
    __builtin_amdgcn_s_setprio(0);
    __builtin_amdgcn_s_barrier(); asm volatile("" ::: "memory");

    // ===== phase 3: read A mi4-7 (8, overwrite af); stage B-half0(i1) + B-half1
#pragma unroll
    for (int m = 0; m < 4; ++m) {
      af[m][0] = *(const bf16x8*)(sb + aoff + (4 + m) * 2048 + c0);
      af[m][1] = *(const bf16x8*)(sb + aoff + (4 + m) * 2048 + c1);
    }
    if (pf) { STG_B(db, 0, 1, t + 1); STG_B(db, 1, 0, t + 1); STG_B(db, 1, 1, t + 1); }
    __builtin_amdgcn_s_barrier(); asm volatile("" ::: "memory");
    __builtin_amdgcn_s_setprio(1);
#pragma unroll
    for (int m = 0; m < 4; ++m)
#pragma unroll
      for (int n = 0; n < 2; ++n) {
        acc[4 + m][n] = MFMA16(af[m][0], bfv[n][0], acc[4 + m][n]);
        acc[4 + m][n] = MFMA16(af[m][1], bfv[n][1], acc[4 + m][n]);
      }
    __builtin_amdgcn_s_setprio(0);
    __builtin_amdgcn_s_barrier(); asm volatile("" ::: "memory");

    // ===== phase 4: no reads/stage; MFMA then per-K-tile vmcnt
    __builtin_amdgcn_s_setprio(1);
#pragma unroll
    for (int m = 0; m < 4; ++m)
#pragma unroll
      for (int n = 2; n < 4; ++n) {
        acc[4 + m][n] = MFMA16(af[m][0], bfv[n][0], acc[4 + m][n]);
        acc[4 + m][n] = MFMA16(af[m][1], bfv[n][1], acc[4 + m][n]);
      }
    __builtin_amdgcn_s_setprio(0);
    asm volatile("s_waitcnt vmcnt(0)" ::: "memory");
    __builtin_amdgcn_s_barrier();
    asm volatile("" ::: "memory");
  }
#undef STG_A
#undef STG_B

  // ---- epilogue: 4 column-strips of 64; strip LDS [256][EP_P] f32 aliases staging
  __syncthreads();
  float* strip = (float*)smem;
  const int bb  = by >> 4;             // batch (16 row-blocks of 256 per batch)
  const int cg0 = (by & 15) * 4;       // first global chunk of this block
#pragma unroll 1
  for (int q = 0; q < 4; ++q) {
    if (wn == q) {
#pragma unroll
      for (int mi = 0; mi < 8; ++mi)
#pragma unroll
        for (int ni = 0; ni < 4; ++ni)
#pragma unroll
          for (int r = 0; r < 4; ++r)
            strip[(wm * 128 + mi * 16 + g * 4 + r) * EP_P + ni * 16 + fr] = acc[mi][ni][r];
    }
    __syncthreads();
    if constexpr (MODE == 0) {
      if (tid < 256) {
        const int col = tid & 63;
        const int ch  = tid >> 6;       // chunk 0..3
        const int d   = bcol + q * 64 + col;
        const float a = pw[d];          // pw[0][d] = a_d
        float s = 0.f;
#pragma unroll 1
        for (int grp = 0; grp < 4; ++grp) {
          float v[16];
#pragma unroll
          for (int u = 0; u < 16; ++u) v[u] = strip[(ch * 64 + grp * 16 + u) * EP_P + col];
#pragma unroll
          for (int u = 0; u < 16; ++u) { s = a * s + v[u]; v[u] = s; }
#pragma unroll
          for (int u = 0; u < 16; ++u) strip[(ch * 64 + grp * 16 + u) * EP_P + col] = v[u];
        }
        cf[((size_t)(bb * NCH + cg0 + ch)) * D_SZ + d] = s;
      }
      __syncthreads();
    }
#pragma unroll
    for (int j = 0; j < 4; ++j) {
      const int u = j * 512 + tid;
      const int row = u >> 3;
      const int cu = (u & 7) * 8;
      f32x4 lo = *(const f32x4*)&strip[row * EP_P + cu];
      f32x4 hi = *(const f32x4*)&strip[row * EP_P + cu + 4];
      bf16x8 h;
#pragma unroll
      for (int jj = 0; jj < 4; ++jj) { h[jj] = (bf16_t)lo[jj]; h[4 + jj] = (bf16_t)hi[jj]; }
      *(bf16x8*)&Cg[(size_t)(brow + row) * 1024 + bcol + q * 64 + cu] = h;
    }
    __syncthreads();
  }
}

// fp32 -> bf16 grid-stride convert
__global__ __launch_bounds__(256)
void conv_bf16_k(const float* __restrict__ src, bf16_t* __restrict__ dst, int n) {
  int i = (blockIdx.x * 256 + threadIdx.x) * 4;
  const int stride = gridDim.x * 256 * 4;
  for (; i < n; i += stride) {
    f32x4 v = *(const f32x4*)(src + i);
    bf16x4 h;
#pragma unroll
    for (int j = 0; j < 4; ++j) h[j] = (bf16_t)v[j];
    *(bf16x4*)(dst + i) = h;
  }
}

// pw[t][d] = a_d^(t+1)
__global__ __launch_bounds__(256)
void pow_k(const float* __restrict__ log_a, float* __restrict__ pw) {
  const int t = blockIdx.x;
  const int d = threadIdx.x * 4;
#pragma unroll
  for (int j = 0; j < 4; ++j)
    pw[t * D_SZ + d + j] = expf(log_a[d + j] * (float)(t + 1));
}

// sequential scan over chunk finals with factor a^CHT, in place
__global__ __launch_bounds__(256)
void scan_carry_k(const float* __restrict__ log_a, float* __restrict__ cf) {
  const int d = blockIdx.x * 256 + threadIdx.x;
  const int b = blockIdx.y;
  const float aT = expf(log_a[d] * (float)CHT);
  float s = 0.f;
  for (int c = 0; c < NCH; ++c) {
    const size_t idx = ((size_t)(b * NCH + c)) * D_SZ + d;
    s = aT * s + cf[idx];
    cf[idx] = s;
  }
}

// states = xb16 + a^(t+1)*S_{c-1}; write bf16 for GEMM2
__global__ __launch_bounds__(128)
void scan_apply_k(const bf16_t* __restrict__ xb16, const float* __restrict__ pw,
                  const float* __restrict__ cf, bf16_t* __restrict__ xs16) {
  const int d8 = threadIdx.x * 8;
  const int l = blockIdx.x;
  const int b = blockIdx.y;
  const int c = l >> 6;
  const int t = l & (CHT - 1);
  const size_t idx = ((size_t)(b * L_SZ + l)) * D_SZ + d8;
  bf16x8 hv = *(const bf16x8*)(xb16 + idx);
  float s[8];
#pragma unroll
  for (int j = 0; j < 8; ++j) s[j] = (float)hv[j];
  if (c > 0) {
    f32x4 p0  = *(const f32x4*)(pw + t * D_SZ + d8);
    f32x4 p1  = *(const f32x4*)(pw + t * D_SZ + d8 + 4);
    const float* cb = cf + ((size_t)(b * NCH + (c - 1))) * D_SZ + d8;
    f32x4 v0 = *(const f32x4*)cb;
    f32x4 v1 = *(const f32x4*)(cb + 4);
#pragma unroll
    for (int j = 0; j < 4; ++j) { s[j] += p0[j] * v0[j]; s[4 + j] += p1[j] * v1[j]; }
  }
  bf16x8 h;
#pragma unroll
  for (int j = 0; j < 8; ++j) h[j] = (bf16_t)s[j];
  *(bf16x8*)(xs16 + idx) = h;
}

// LayerNorm over D=1024 (bf16 input, fp32 output), one block per row
__global__ __launch_bounds__(256)
void ln_k(const bf16_t* __restrict__ y, const float* __restrict__ gamma,
          const float* __restrict__ beta, float* __restrict__ out) {
  const size_t row = blockIdx.x;
  const int tid = threadIdx.x;
  bf16x4 h = *(const bf16x4*)(y + row * D_SZ + tid * 4);
  float v[4];
#pragma unroll
  for (int j = 0; j < 4; ++j) v[j] = (float)h[j];
  float s  = v[0] + v[1] + v[2] + v[3];
  float sq = v[0] * v[0] + v[1] * v[1] + v[2] * v[2] + v[3] * v[3];
#pragma unroll
  for (int off = 32; off; off >>= 1) {
    s  += __shfl_down(s, off);
    sq += __shfl_down(sq, off);
  }
  __shared__ float red[8];
  const int wid = tid >> 6;
  if ((tid & 63) == 0) { red[wid] = s; red[4 + wid] = sq; }
  __syncthreads();
  s  = red[0] + red[1] + red[2] + red[3];
  sq = red[4] + red[5] + red[6] + red[7];
  const float mean = s * (1.f / D_SZ);
  const float var  = sq * (1.f / D_SZ) - mean * mean;
  const float inv  = rsqrtf(var + 1e-5f);
  f32x4 gm = *(const f32x4*)(gamma + tid * 4);
  f32x4 bt = *(const f32x4*)(beta  + tid * 4);
  f32x4 o;
#pragma unroll
  for (int j = 0; j < 4; ++j) o[j] = (v[j] - mean) * inv * gm[j] + bt[j];
  *(f32x4*)(out + row * D_SZ + tid * 4) = o;
}

extern "C" void kernel_launch(void* const* d_in, const int* in_sizes, int n_in,
                              void* d_out, int out_size, void* d_ws, size_t ws_size,
                              hipStream_t stream) {
  const float* u     = (const float*)d_in[0];
  const float* log_a = (const float*)d_in[1];
  const float* W_b   = (const float*)d_in[2];
  const float* W_c   = (const float*)d_in[3];
  const float* gamma = (const float*)d_in[4];
  const float* beta  = (const float*)d_in[5];
  float* out = (float*)d_out;

  const size_t NBLD = (size_t)B_SZ * L_SZ * D_SZ;
  bf16_t* u16  = (bf16_t*)d_ws;             // bf16 u; xs16 aliases after GEMM1
  bf16_t* xb16 = u16 + NBLD;                // GEMM1 out (locally scanned); y16 aliases
  bf16_t* wb16 = xb16 + NBLD;
  bf16_t* wc16 = wb16 + (size_t)D_SZ * D_SZ;
  float*  cf   = (float*)(wc16 + (size_t)D_SZ * D_SZ);
  float*  pw   = cf + (size_t)B_SZ * NCH * D_SZ;
  bf16_t* xs16 = u16;                       // u16 dead after GEMM1
  bf16_t* y16  = xb16;                      // xb16 dead after apply

  const int nblk = (B_SZ * L_SZ / BM) * (D_SZ / BN);   // 512

  conv_bf16_k<<<2048, 256, 0, stream>>>(u, u16, (int)NBLD);
  conv_bf16_k<<<512, 256, 0, stream>>>(W_b, wb16, D_SZ * D_SZ);
  conv_bf16_k<<<512, 256, 0, stream>>>(W_c, wc16, D_SZ * D_SZ);
  pow_k<<<CHT, 256, 0, stream>>>(log_a, pw);

  gemm256<0><<<nblk, 512, 0, stream>>>(u16, wb16, xb16, pw, cf);
  scan_carry_k<<<dim3(D_SZ / 256, B_SZ), 256, 0, stream>>>(log_a, cf);
  scan_apply_k<<<dim3(L_SZ, B_SZ), 128, 0, stream>>>(xb16, pw, cf, xs16);
  gemm256<1><<<nblk, 512, 0, stream>>>(xs16, wc16, y16, nullptr, nullptr);
  ln_k<<<B_SZ * L_SZ, 256, 0, stream>>>(y16, gamma, beta, out);
}